// Round 9
// baseline (1355.866 us; speedup 1.0000x reference)
//
#include <hip/hip_runtime.h>

#define NTOK 8192
#define DDIM 1024
#define HDIM 2048
#define NEXP 8
#define GEXP 2                  // experts per group (h' = 67 MB, L3-resident)

typedef unsigned short u16;
typedef short bf16x8 __attribute__((ext_vector_type(8)));
typedef float f32x4 __attribute__((ext_vector_type(4)));
typedef float float4_t __attribute__((ext_vector_type(4)));

__device__ __forceinline__ u16 f2bf(float f) {
  unsigned u = __float_as_uint(f);
  u += 0x7FFFu + ((u >> 16) & 1u);   // round-to-nearest-even
  return (u16)(u >> 16);
}

#define GLOAD_LDS16(gp, lp)                                                     \
  __builtin_amdgcn_global_load_lds(                                             \
      (const __attribute__((address_space(1))) unsigned int*)(gp),              \
      (__attribute__((address_space(3))) unsigned int*)(lp), 16, 0, 0)

// ------------------------------------------------ fused x->bf16 convert + gate
__global__ void k_prep(const float* __restrict__ x, const float* __restrict__ Wg,
                       const float* __restrict__ bg,
                       u16* __restrict__ xb, float* __restrict__ gate) {
  const int tok = (blockIdx.x * 256 + threadIdx.x) >> 6;
  const int lane = threadIdx.x & 63;
  const float* xr = x + (size_t)tok * DDIM;
  u16* xo = xb + (size_t)tok * DDIM;
  float s[NEXP];
#pragma unroll
  for (int e = 0; e < NEXP; ++e) s[e] = 0.f;
#pragma unroll
  for (int it = 0; it < 2; ++it) {
    const int d0 = lane * 8 + it * 512;
    float4_t v0 = *(const float4_t*)(xr + d0);
    float4_t v1 = *(const float4_t*)(xr + d0 + 4);
    union { bf16x8 v; u16 h[8]; } u;
    u.h[0] = f2bf(v0.x); u.h[1] = f2bf(v0.y); u.h[2] = f2bf(v0.z); u.h[3] = f2bf(v0.w);
    u.h[4] = f2bf(v1.x); u.h[5] = f2bf(v1.y); u.h[6] = f2bf(v1.z); u.h[7] = f2bf(v1.w);
    *(bf16x8*)(xo + d0) = u.v;
    float xv[8] = {v0.x, v0.y, v0.z, v0.w, v1.x, v1.y, v1.z, v1.w};
#pragma unroll
    for (int j = 0; j < 8; ++j) {
      const float4_t w0 = *(const float4_t*)(Wg + (size_t)(d0 + j) * NEXP);
      const float4_t w1 = *(const float4_t*)(Wg + (size_t)(d0 + j) * NEXP + 4);
      s[0] += xv[j] * w0.x; s[1] += xv[j] * w0.y;
      s[2] += xv[j] * w0.z; s[3] += xv[j] * w0.w;
      s[4] += xv[j] * w1.x; s[5] += xv[j] * w1.y;
      s[6] += xv[j] * w1.z; s[7] += xv[j] * w1.w;
    }
  }
#pragma unroll
  for (int off = 32; off; off >>= 1)
#pragma unroll
    for (int e = 0; e < NEXP; ++e) s[e] += __shfl_down(s[e], off);
  if (lane == 0) {
#pragma unroll
    for (int e = 0; e < NEXP; ++e) gate[(size_t)tok * NEXP + e] = s[e] + bg[e];
  }
}

// ------------- vectorized transpose+convert: out[z*oexp + c*orstride + r] = in[z][r][c]
__global__ void k_transpose(const float* __restrict__ in, u16* __restrict__ out,
                            int R, int C, size_t oexp, int orstride) {
  __shared__ float t[64][65];
  const int rb = blockIdx.x * 64, cb = blockIdx.y * 64;
  const float* pin = in + (size_t)blockIdx.z * R * C;
  u16* pout = out + (size_t)blockIdx.z * oexp;
  const int tid = threadIdx.x;
  {
    const int r = tid >> 4;
    const int c4 = (tid & 15) * 4;
#pragma unroll
    for (int i = 0; i < 4; ++i) {
      float4_t v = *(const float4_t*)(pin + (size_t)(rb + r + 16 * i) * C + cb + c4);
      t[r + 16 * i][c4 + 0] = v.x;
      t[r + 16 * i][c4 + 1] = v.y;
      t[r + 16 * i][c4 + 2] = v.z;
      t[r + 16 * i][c4 + 3] = v.w;
    }
  }
  __syncthreads();
  {
    const int oc = tid >> 3;
    const int r8 = (tid & 7) * 8;
#pragma unroll
    for (int jp = 0; jp < 2; ++jp) {
      const int ocol = oc + 32 * jp;
      union { bf16x8 v; u16 h[8]; } u;
#pragma unroll
      for (int k = 0; k < 8; ++k) u.h[k] = f2bf(t[r8 + k][ocol]);
      *(bf16x8*)(pout + (size_t)(cb + ocol) * orstride + rb + r8) = u.v;
    }
  }
}

// =========== GEMM: A direct global->VGPR (reg double-buffer), B via LDS (3-buf).
// TM = NWM*64, TN = NWN*64; 8 waves NWM x NWN; wave-tile 64x64.
// MODE 1: h' = bf16(gate*relu(acc+bias)); MODE 2: out f32 (+)= acc (+gate.b2)
// BCH: B K-dim spans per-expert [e][*][HDIM] blocks.
template <int NWM, int NWN, int MODE, int BCH>
__global__ __launch_bounds__(512, 2) void k_gemm(
    const u16* __restrict__ A, int lda,
    const u16* __restrict__ Bt, int ldb,
    const float* __restrict__ bias,
    const float* __restrict__ gate, int ebase,
    void* __restrict__ Cout, int ldc,
    int K, int accum, int ca, int cb, int cgcols) {
  constexpr int TM = NWM * 64;
  constexpr int TN = NWN * 64;
  constexpr int NB = TN / 64;                     // B glds per K-tile
  constexpr int BUFE = TN * 64;                   // B buffer elems
  __shared__ __align__(16) u16 lds[3 * BUFE];     // B only: 48 / 96 KiB
  const int tid = threadIdx.x, lane = tid & 63, wid = tid >> 6;
  const int wm = wid / NWN, wn = wid % NWN;

  // XCD supertiled ordering: chunk = ca x cb tiles, tn-inner
  const int wg = blockIdx.x;
  const int xcd = wg & 7, lo = wg >> 3;
  const int cr = xcd / cgcols, cc = xcd % cgcols;
  const int tm = cr * ca + lo / cb;
  const int tn = cc * cb + lo % cb;
  const int bm = tm * TM, bn = tn * TN;

  // B staging: linear LDS dest + inverse-swizzled global source (rule 21)
  const int srow = tid >> 3;
  const int scol = ((tid & 7) ^ (srow & 7)) << 3;
  const u16* gB = Bt + (size_t)(bn + srow) * ldb + scol;
  const int dofs = wid * 512;

  // A per-lane direct-load base: lane (fr,fq) -> row bm+wm*64+fr, k-slot fq*8
  const int fr = lane & 15, fq = lane >> 4, xr = fr & 7;
  const u16* gAa = A + (size_t)(bm + wm * 64 + fr) * lda + fq * 8;

  u16* b0 = lds;
  u16* b1 = lds + BUFE;
  u16* b2 = lds + 2 * BUFE;

#define BOFF(kt) (BCH ? ((size_t)((kt) >> 5) * ((size_t)DDIM * HDIM) +          \
                         (size_t)((kt) & 31) * 64)                              \
                      : (size_t)(kt) * 64)
#define STAGE_B(dst, kt)                                                        \
  { _Pragma("unroll") for (int c_ = 0; c_ < NB; ++c_)                           \
      GLOAD_LDS16(gB + (size_t)(c_ * 64) * ldb + BOFF(kt),                      \
                  (dst) + c_ * 4096 + dofs); }
#define LOAD_A(dst, kt)                                                         \
  { _Pragma("unroll") for (int mi_ = 0; mi_ < 4; ++mi_)                         \
    _Pragma("unroll") for (int kk_ = 0; kk_ < 2; ++kk_)                         \
      (dst)[mi_ * 2 + kk_] = *(const bf16x8*)(gAa +                             \
          (size_t)(mi_ * 16) * lda + (size_t)(kt) * 64 + kk_ * 32); }
#define VMW_NB()                                                                \
  { if (NB == 2) asm volatile("s_waitcnt vmcnt(2)" ::: "memory");               \
    else         asm volatile("s_waitcnt vmcnt(4)" ::: "memory"); }

  // swizzled B fragment read offsets
  const int so0 = ((0 + fq) ^ xr) << 3;
  const int so1 = ((4 + fq) ^ xr) << 3;

  f32x4 acc[4][4] = {};
  const int nkt = K >> 6;       // 16 or 64 (even)

  bf16x8 aA[8], aB[8];

  // prologue: B(0), A(0), B(1) -> wait leaves B(1) in flight
  STAGE_B(b0, 0);
  LOAD_A(aA, 0);
  STAGE_B(b1, 1);
  u16 *bC = b0, *bN = b1, *bF = b2;

#define TILE_BODY(t, aU, aL)                                                    \
  {                                                                             \
    if ((t) == nkt - 1) { asm volatile("s_waitcnt vmcnt(0)" ::: "memory"); }    \
    else                { VMW_NB(); }                                           \
    __builtin_amdgcn_s_barrier();                                               \
    __builtin_amdgcn_sched_barrier(0);                                          \
    if ((t) + 1 < nkt) LOAD_A(aL, (t) + 1);                                     \
    if ((t) + 2 < nkt) STAGE_B(bF, (t) + 2);                                    \
    bf16x8 bv[4][2];                                                            \
    _Pragma("unroll") for (int ni_ = 0; ni_ < 4; ++ni_) {                       \
      const int rb_ = (wn * 64 + ni_ * 16 + fr) << 6;                           \
      bv[ni_][0] = *(const bf16x8*)(bC + rb_ + so0);                            \
      bv[ni_][1] = *(const bf16x8*)(bC + rb_ + so1);                            \
    }                                                                           \
    __builtin_amdgcn_s_setprio(1);                                              \
    _Pragma("unroll") for (int mi_ = 0; mi_ < 4; ++mi_)                         \
    _Pragma("unroll") for (int ni_ = 0; ni_ < 4; ++ni_) {                       \
      acc[mi_][ni_] = __builtin_amdgcn_mfma_f32_16x16x32_bf16(                  \
          (aU)[mi_ * 2 + 0], bv[ni_][0], acc[mi_][ni_], 0, 0, 0);               \
      acc[mi_][ni_] = __builtin_amdgcn_mfma_f32_16x16x32_bf16(                  \
          (aU)[mi_ * 2 + 1], bv[ni_][1], acc[mi_][ni_], 0, 0, 0);               \
    }                                                                           \
    __builtin_amdgcn_s_setprio(0);                                              \
    u16* tp_ = bC; bC = bN; bN = bF; bF = tp_;                                  \
  }

#pragma unroll 1
  for (int tp = 0; tp < nkt; tp += 2) {
    TILE_BODY(tp, aA, aB);
    TILE_BODY(tp + 1, aB, aA);
  }

  // ---------------- epilogue; C/D layout: col=lane&15, row=(lane>>4)*4+j
  if (MODE == 1) {
    u16* O = (u16*)Cout;
    const int e = ebase + (bn >> 11);   // TN=128 tile lies within one expert
    float bcol[4];
#pragma unroll
    for (int ni = 0; ni < 4; ++ni) bcol[ni] = bias[bn + wn * 64 + ni * 16 + fr];
#pragma unroll
    for (int mi = 0; mi < 4; ++mi) {
#pragma unroll
      for (int j = 0; j < 4; ++j) {
        const int r = bm + wm * 64 + mi * 16 + fq * 4 + j;
        const float g = gate[(size_t)r * NEXP + e];
#pragma unroll
        for (int ni = 0; ni < 4; ++ni) {
          float v = fmaxf(acc[mi][ni][j] + bcol[ni], 0.f) * g;
          O[(size_t)r * ldc + bn + wn * 64 + ni * 16 + fr] = f2bf(v);
        }
      }
    }
  } else {
    float* O = (float*)Cout;
    float b2c[4][NEXP];
    if (!accum) {
#pragma unroll
      for (int ni = 0; ni < 4; ++ni)
#pragma unroll
        for (int e = 0; e < NEXP; ++e)
          b2c[ni][e] = bias[(size_t)e * DDIM + bn + wn * 64 + ni * 16 + fr];
    }
#pragma unroll
    for (int mi = 0; mi < 4; ++mi) {
#pragma unroll
      for (int j = 0; j < 4; ++j) {
        const int r = bm + wm * 64 + mi * 16 + fq * 4 + j;
        if (!accum) {
          float g8[NEXP];
#pragma unroll
          for (int e = 0; e < NEXP; ++e) g8[e] = gate[(size_t)r * NEXP + e];
#pragma unroll
          for (int ni = 0; ni < 4; ++ni) {
            float v = acc[mi][ni][j];
#pragma unroll
            for (int e = 0; e < NEXP; ++e) v += g8[e] * b2c[ni][e];
            O[(size_t)r * DDIM + bn + wn * 64 + ni * 16 + fr] = v;
          }
        } else {
#pragma unroll
          for (int ni = 0; ni < 4; ++ni) {
            const size_t idx = (size_t)r * DDIM + bn + wn * 64 + ni * 16 + fr;
            O[idx] += acc[mi][ni][j];
          }
        }
      }
    }
  }
#undef TILE_BODY
#undef STAGE_B
#undef LOAD_A
#undef VMW_NB
#undef BOFF
}

extern "C" void kernel_launch(void* const* d_in, const int* in_sizes, int n_in,
                              void* d_out, int out_size, void* d_ws, size_t ws_size,
                              hipStream_t stream) {
  (void)in_sizes; (void)n_in; (void)out_size;
  const float* x  = (const float*)d_in[0];   // [N, D]
  const float* W1 = (const float*)d_in[1];   // [E, D, H]
  const float* b1 = (const float*)d_in[2];   // [E, H]
  const float* W2 = (const float*)d_in[3];   // [E, H, D]
  const float* b2 = (const float*)d_in[4];   // [E, D]
  const float* Wg = (const float*)d_in[5];   // [D, E]
  const float* bg = (const float*)d_in[6];   // [E]
  float* out = (float*)d_out;                // [N, D]

  size_t o_xb   = 0;
  size_t o_w1t  = o_xb  + (size_t)NTOK * DDIM * 2;          // xb   bf16 [N,D]
  size_t o_w2t  = o_w1t + (size_t)NEXP * HDIM * DDIM * 2;   // W1t  bf16 [E*H, D]
  size_t o_gate = o_w2t + (size_t)NEXP * DDIM * HDIM * 2;   // W2t  bf16 [E][D][H]
  size_t o_h    = o_gate + (size_t)NTOK * NEXP * 4;         // gate f32  [N, E]
  size_t need   = o_h   + (size_t)NTOK * GEXP * HDIM * 2;   // h'   bf16 [N, G*H]
  if (ws_size < need) return;

  u16*   xb   = (u16*)((char*)d_ws + o_xb);
  u16*   W1t  = (u16*)((char*)d_ws + o_w1t);
  u16*   W2t  = (u16*)((char*)d_ws + o_w2t);
  float* gate = (float*)((char*)d_ws + o_gate);
  u16*   hbuf = (u16*)((char*)d_ws + o_h);

  k_prep<<<NTOK / 4, 256, 0, stream>>>(x, Wg, bg, xb, gate);
  dim3 g1(DDIM / 64, HDIM / 64, NEXP);
  k_transpose<<<g1, 256, 0, stream>>>(W1, W1t, DDIM, HDIM, (size_t)HDIM * DDIM, DDIM);
  dim3 g2(HDIM / 64, DDIM / 64, NEXP);
  k_transpose<<<g2, 256, 0, stream>>>(W2, W2t, HDIM, DDIM, (size_t)DDIM * HDIM, HDIM);

  const int Ng = GEXP * HDIM;                  // 4096
  for (int g = 0; g < NEXP / GEXP; ++g) {
    // GEMM1: 256x128 tiles (4Mx2N waves), grid 32tm x 32tn = 1024; chunks 16x8
    k_gemm<4, 2, 1, 0><<<1024, 512, 0, stream>>>(
        xb, DDIM, W1t + (size_t)g * Ng * DDIM, DDIM,
        b1 + (size_t)g * Ng, gate, g * GEXP,
        hbuf, Ng, DDIM, 0, 16, 8, 4);
    // GEMM2: 128x256 tiles (2Mx4N waves), grid 64tm x 4tn = 256; chunks 8x4
    k_gemm<2, 4, 2, 1><<<256, 512, 0, stream>>>(
        hbuf, Ng, W2t + (size_t)g * GEXP * DDIM * HDIM, HDIM,
        b2, gate, 0,
        out, DDIM, Ng, g > 0, 8, 4, 1);
  }
}

// Round 10
// 630.773 us; speedup vs baseline: 2.1495x; 2.1495x over previous
//
#include <hip/hip_runtime.h>

#define NTOK 8192
#define DDIM 1024
#define HDIM 2048
#define NEXP 8
#define GEXP 2                  // experts per group
#define G1_NKT 16               // K=1024 / 64
#define G2_NKT 64               // K=4096 / 64

typedef unsigned short u16;
typedef short bf16x8 __attribute__((ext_vector_type(8)));
typedef float f32x4 __attribute__((ext_vector_type(4)));
typedef float float4_t __attribute__((ext_vector_type(4)));

__device__ __forceinline__ u16 f2bf(float f) {
  unsigned u = __float_as_uint(f);
  u += 0x7FFFu + ((u >> 16) & 1u);   // round-to-nearest-even
  return (u16)(u >> 16);
}

#define GLOAD_LDS16(gp, lp)                                                     \
  __builtin_amdgcn_global_load_lds(                                             \
      (const __attribute__((address_space(1))) unsigned int*)(gp),              \
      (__attribute__((address_space(3))) unsigned int*)(lp), 16, 0, 0)

#define VMW(n) asm volatile("s_waitcnt vmcnt(" #n ")" ::: "memory")
#define ENTRYB()                                                                \
  { __builtin_amdgcn_s_barrier(); __builtin_amdgcn_sched_barrier(0); }

// ------------------------------------------------ fused x->bf16 convert + gate
__global__ void k_prep(const float* __restrict__ x, const float* __restrict__ Wg,
                       const float* __restrict__ bg,
                       u16* __restrict__ xb, float* __restrict__ gate) {
  const int tok = (blockIdx.x * 256 + threadIdx.x) >> 6;
  const int lane = threadIdx.x & 63;
  const float* xr = x + (size_t)tok * DDIM;
  u16* xo = xb + (size_t)tok * DDIM;
  float s[NEXP];
#pragma unroll
  for (int e = 0; e < NEXP; ++e) s[e] = 0.f;
#pragma unroll
  for (int it = 0; it < 2; ++it) {
    const int d0 = lane * 8 + it * 512;
    float4_t v0 = *(const float4_t*)(xr + d0);
    float4_t v1 = *(const float4_t*)(xr + d0 + 4);
    union { bf16x8 v; u16 h[8]; } u;
    u.h[0] = f2bf(v0.x); u.h[1] = f2bf(v0.y); u.h[2] = f2bf(v0.z); u.h[3] = f2bf(v0.w);
    u.h[4] = f2bf(v1.x); u.h[5] = f2bf(v1.y); u.h[6] = f2bf(v1.z); u.h[7] = f2bf(v1.w);
    *(bf16x8*)(xo + d0) = u.v;
    float xv[8] = {v0.x, v0.y, v0.z, v0.w, v1.x, v1.y, v1.z, v1.w};
#pragma unroll
    for (int j = 0; j < 8; ++j) {
      const float4_t w0 = *(const float4_t*)(Wg + (size_t)(d0 + j) * NEXP);
      const float4_t w1 = *(const float4_t*)(Wg + (size_t)(d0 + j) * NEXP + 4);
      s[0] += xv[j] * w0.x; s[1] += xv[j] * w0.y;
      s[2] += xv[j] * w0.z; s[3] += xv[j] * w0.w;
      s[4] += xv[j] * w1.x; s[5] += xv[j] * w1.y;
      s[6] += xv[j] * w1.z; s[7] += xv[j] * w1.w;
    }
  }
#pragma unroll
  for (int off = 32; off; off >>= 1)
#pragma unroll
    for (int e = 0; e < NEXP; ++e) s[e] += __shfl_down(s[e], off);
  if (lane == 0) {
#pragma unroll
    for (int e = 0; e < NEXP; ++e) gate[(size_t)tok * NEXP + e] = s[e] + bg[e];
  }
}

// ------------- vectorized transpose+convert: out[z*oexp + c*orstride + r] = in[z][r][c]
__global__ void k_transpose(const float* __restrict__ in, u16* __restrict__ out,
                            int R, int C, size_t oexp, int orstride) {
  __shared__ float t[64][65];
  const int rb = blockIdx.x * 64, cb = blockIdx.y * 64;
  const float* pin = in + (size_t)blockIdx.z * R * C;
  u16* pout = out + (size_t)blockIdx.z * oexp;
  const int tid = threadIdx.x;
  {
    const int r = tid >> 4;
    const int c4 = (tid & 15) * 4;
#pragma unroll
    for (int i = 0; i < 4; ++i) {
      float4_t v = *(const float4_t*)(pin + (size_t)(rb + r + 16 * i) * C + cb + c4);
      t[r + 16 * i][c4 + 0] = v.x;
      t[r + 16 * i][c4 + 1] = v.y;
      t[r + 16 * i][c4 + 2] = v.z;
      t[r + 16 * i][c4 + 3] = v.w;
    }
  }
  __syncthreads();
  {
    const int oc = tid >> 3;
    const int r8 = (tid & 7) * 8;
#pragma unroll
    for (int jp = 0; jp < 2; ++jp) {
      const int ocol = oc + 32 * jp;
      union { bf16x8 v; u16 h[8]; } u;
#pragma unroll
      for (int k = 0; k < 8; ++k) u.h[k] = f2bf(t[r8 + k][ocol]);
      *(bf16x8*)(pout + (size_t)(cb + ocol) * orstride + rb + r8) = u.v;
    }
  }
}

// ============ GEMM1: 256x256 tile, 4-phase snake, operand reuse, 1 barrier/phase
// (no forced lgkmcnt(0): compiler emits fine-grained lgkm waits before each MFMA)
// h'[m][4096] = bf16(gate * relu(x . W1t^T + b1))
__global__ __launch_bounds__(512, 2) void k_g1(
    const u16* __restrict__ A, const u16* __restrict__ Bt,
    const float* __restrict__ bias, const float* __restrict__ gate,
    int ebase, u16* __restrict__ Cout) {
  __shared__ __align__(16) u16 lds[65536];   // 128 KiB: 2 buf x (A 256 | B 256) x 64
  const int tid = threadIdx.x, lane = tid & 63, wid = tid >> 6;
  const int wm = wid >> 2, wn = wid & 3;
  // XCD supertile: 32tm x 16tn grid; 8 chunks of 8x8, tn-inner
  const int wg = blockIdx.x;
  const int xcd = wg & 7, lo = wg >> 3;
  const int tm = (xcd >> 1) * 8 + (lo >> 3);
  const int tn = (xcd & 1) * 8 + (lo & 7);
  const int bm = tm * 256, bn = tn * 256;

  const int srow = tid >> 3;
  const int scol = ((tid & 7) ^ (srow & 7)) << 3;
  const u16* gA = A + (size_t)(bm + srow) * 1024 + scol;
  const u16* gB = Bt + (size_t)(bn + srow) * 1024 + scol;
  const int dofs = wid * 512;

  u16* aB0 = lds;          u16* bB0 = lds + 16384;
  u16* aB1 = lds + 32768;  u16* bB1 = lds + 49152;

  const int fr = lane & 15, fq = lane >> 4, xr = fr & 7;
  const int so0 = ((0 + fq) ^ xr) << 3;
  const int so1 = ((4 + fq) ^ xr) << 3;

  f32x4 acc[4][4][2] = {};
  bf16x8 av[4][2], bv[2][2];

#define G1_SA(dst, hh, ts)                                                      \
  { GLOAD_LDS16(gA + (size_t)((hh)*128     ) * 1024 + (size_t)(ts) * 64,        \
                (dst) + ((hh)*128     ) * 64 + dofs);                           \
    GLOAD_LDS16(gA + (size_t)((hh)*128 + 64) * 1024 + (size_t)(ts) * 64,        \
                (dst) + ((hh)*128 + 64) * 64 + dofs); }
#define G1_SB(dst, hh, ts)                                                      \
  { GLOAD_LDS16(gB + (size_t)((hh)*128     ) * 1024 + (size_t)(ts) * 64,        \
                (dst) + ((hh)*128     ) * 64 + dofs);                           \
    GLOAD_LDS16(gB + (size_t)((hh)*128 + 64) * 1024 + (size_t)(ts) * 64,        \
                (dst) + ((hh)*128 + 64) * 64 + dofs); }
#define RD_A(src, MH)                                                           \
  { _Pragma("unroll") for (int i_ = 0; i_ < 4; ++i_) {                          \
      const int rb_ = ((MH)*128 + wm * 64 + i_ * 16 + fr) << 6;                 \
      av[i_][0] = *(const bf16x8*)((src) + rb_ + so0);                          \
      av[i_][1] = *(const bf16x8*)((src) + rb_ + so1); } }
#define RD_B(src, NH)                                                           \
  { _Pragma("unroll") for (int n_ = 0; n_ < 2; ++n_) {                          \
      const int rb_ = ((NH)*128 + wn * 32 + n_ * 16 + fr) << 6;                 \
      bv[n_][0] = *(const bf16x8*)((src) + rb_ + so0);                          \
      bv[n_][1] = *(const bf16x8*)((src) + rb_ + so1); } }
#define MMA16(Q)                                                                \
  { __builtin_amdgcn_s_setprio(1);                                              \
    _Pragma("unroll") for (int i_ = 0; i_ < 4; ++i_)                            \
    _Pragma("unroll") for (int n_ = 0; n_ < 2; ++n_) {                          \
      acc[Q][i_][n_] = __builtin_amdgcn_mfma_f32_16x16x32_bf16(                 \
          av[i_][0], bv[n_][0], acc[Q][i_][n_], 0, 0, 0);                       \
      acc[Q][i_][n_] = __builtin_amdgcn_mfma_f32_16x16x32_bf16(                 \
          av[i_][1], bv[n_][1], acc[Q][i_][n_], 0, 0, 0); }                     \
    __builtin_amdgcn_s_setprio(0); }

  // prologue: tile0, issue order A0,B0,A1,B1 (matches steady-state order)
  G1_SA(aB0, 0, 0); G1_SB(bB0, 0, 0); G1_SA(aB0, 1, 0); G1_SB(bB0, 1, 0);

  u16 *aC_ = aB0, *bC_ = bB0, *aN_ = aB1, *bN_ = bB1;

#pragma unroll 1
  for (int t = 0; t < G1_NKT; ++t) {
    const bool s1 = (t + 1 < G1_NKT);
    // p0 = (M0,N0): needs A0(t),B0(t); stages A0(t+1)
    VMW(4); ENTRYB();
    RD_A(aC_, 0); RD_B(bC_, 0);
    if (s1) G1_SA(aN_, 0, t + 1);
    MMA16(0);
    // p1 = (M1,N0): needs A1(t); B0 reused in regs; stages B0(t+1)
    if (s1) { VMW(4); } else { VMW(2); }
    ENTRYB();
    RD_A(aC_, 1);
    if (s1) G1_SB(bN_, 0, t + 1);
    MMA16(2);
    // p2 = (M1,N1): needs B1(t); A1 reused; stages A1(t+1)
    if (s1) { VMW(4); } else { VMW(0); }
    ENTRYB();
    RD_B(bC_, 1);
    if (s1) G1_SA(aN_, 1, t + 1);
    MMA16(3);
    // p3 = (M0,N1): re-reads A0(t) (stable); B1 reused; stages B1(t+1); NO barrier
    RD_A(aC_, 0);
    if (s1) G1_SB(bN_, 1, t + 1);
    MMA16(1);
    u16* tp;
    tp = aC_; aC_ = aN_; aN_ = tp;
    tp = bC_; bC_ = bN_; bN_ = tp;
  }

  // epilogue; C/D layout: col=lane&15, row=(lane>>4)*4+j
#pragma unroll
  for (int q = 0; q < 4; ++q) {
    const int MH = q >> 1, NH = q & 1;
    const int cb0 = bn + NH * 128 + wn * 32;
    const int e = ebase + (cb0 >> 11);
    float bcol[2];
#pragma unroll
    for (int n = 0; n < 2; ++n) bcol[n] = bias[cb0 + n * 16 + fr];
#pragma unroll
    for (int i = 0; i < 4; ++i) {
#pragma unroll
      for (int j = 0; j < 4; ++j) {
        const int r = bm + MH * 128 + wm * 64 + i * 16 + fq * 4 + j;
        const float g = gate[(size_t)r * NEXP + e];
#pragma unroll
        for (int n = 0; n < 2; ++n) {
          float v = fmaxf(acc[q][i][n][j] + bcol[n], 0.f) * g;
          Cout[(size_t)r * (GEXP * HDIM) + cb0 + n * 16 + fr] = f2bf(v);
        }
      }
    }
  }
#undef G1_SA
#undef G1_SB
#undef RD_A
#undef RD_B
#undef MMA16
}

// ============ GEMM2: 128x256 tile, 2 fat phases (N-halves), A held in regs
// (no forced lgkmcnt(0))
// out[m][1024] (+)= h' . W2t^T  (+ sum_e gate*b2 when !accum)
__global__ __launch_bounds__(512, 2) void k_g2(
    const u16* __restrict__ A, const u16* __restrict__ Bt,
    const float* __restrict__ bias, const float* __restrict__ gate,
    float* __restrict__ Cout, int accum) {
  __shared__ __align__(16) u16 lds[49152];   // 96 KiB: 2 buf x (A 128 | B 256) x 64
  const int tid = threadIdx.x, lane = tid & 63, wid = tid >> 6;
  const int wm = wid >> 2, wn = wid & 3;
  // XCD supertile: 64tm x 4tn grid; 8 chunks of 8x4, tn-inner
  const int wg = blockIdx.x;
  const int xcd = wg & 7, lo = wg >> 3;
  const int tm = xcd * 8 + (lo >> 2);
  const int tn = lo & 3;
  const int bm = tm * 128, bn = tn * 256;

  const int srow = tid >> 3;
  const int scol = ((tid & 7) ^ (srow & 7)) << 3;
  const u16* gA = A + (size_t)(bm + srow) * (GEXP * HDIM) + scol;
  const u16* gB = Bt + (size_t)(bn + srow) * HDIM + scol;
  const int dofs = wid * 512;

  u16* aB0 = lds;          u16* bB0 = lds + 8192;
  u16* aB1 = lds + 24576;  u16* bB1 = lds + 32768;

  const int fr = lane & 15, fq = lane >> 4, xr = fr & 7;
  const int so0 = ((0 + fq) ^ xr) << 3;
  const int so1 = ((4 + fq) ^ xr) << 3;

  f32x4 acc[2][4][2] = {};
  bf16x8 av[4][2], bv[2][2];

#define G2_BOFF(ts) ((size_t)((ts) >> 5) * ((size_t)DDIM * HDIM) +              \
                     (size_t)((ts) & 31) * 64)
#define G2_SA(dst, ts)                                                          \
  { GLOAD_LDS16(gA + (size_t)(ts) * 64, (dst) + dofs);                          \
    GLOAD_LDS16(gA + (size_t)64 * (GEXP * HDIM) + (size_t)(ts) * 64,            \
                (dst) + 4096 + dofs); }
#define G2_SB(dst, hh, ts)                                                      \
  { GLOAD_LDS16(gB + (size_t)((hh)*128     ) * HDIM + G2_BOFF(ts),              \
                (dst) + ((hh)*128     ) * 64 + dofs);                           \
    GLOAD_LDS16(gB + (size_t)((hh)*128 + 64) * HDIM + G2_BOFF(ts),              \
                (dst) + ((hh)*128 + 64) * 64 + dofs); }
#define G2_RDA(src)                                                             \
  { _Pragma("unroll") for (int i_ = 0; i_ < 4; ++i_) {                          \
      const int rb_ = (wm * 64 + i_ * 16 + fr) << 6;                            \
      av[i_][0] = *(const bf16x8*)((src) + rb_ + so0);                          \
      av[i_][1] = *(const bf16x8*)((src) + rb_ + so1); } }
#define G2_RDB(src, NH)                                                         \
  { _Pragma("unroll") for (int n_ = 0; n_ < 2; ++n_) {                          \
      const int rb_ = ((NH)*128 + wn * 32 + n_ * 16 + fr) << 6;                 \
      bv[n_][0] = *(const bf16x8*)((src) + rb_ + so0);                          \
      bv[n_][1] = *(const bf16x8*)((src) + rb_ + so1); } }
#define G2_MMA(Q)                                                               \
  { __builtin_amdgcn_s_setprio(1);                                              \
    _Pragma("unroll") for (int i_ = 0; i_ < 4; ++i_)                            \
    _Pragma("unroll") for (int n_ = 0; n_ < 2; ++n_) {                          \
      acc[Q][i_][n_] = __builtin_amdgcn_mfma_f32_16x16x32_bf16(                 \
          av[i_][0], bv[n_][0], acc[Q][i_][n_], 0, 0, 0);                       \
      acc[Q][i_][n_] = __builtin_amdgcn_mfma_f32_16x16x32_bf16(                 \
          av[i_][1], bv[n_][1], acc[Q][i_][n_], 0, 0, 0); }                     \
    __builtin_amdgcn_s_setprio(0); }

  // prologue: tile0, issue order A,B0,B1 (matches steady state)
  G2_SA(aB0, 0); G2_SB(bB0, 0, 0); G2_SB(bB0, 1, 0);

  u16 *aC_ = aB0, *bC_ = bB0, *aN_ = aB1, *bN_ = bB1;

#pragma unroll 1
  for (int t = 0; t < G2_NKT; ++t) {
    const bool s1 = (t + 1 < G2_NKT);
    // p0 (N0): needs A(t),B0(t); stages A(t+1)+B0(t+1)
    VMW(2); ENTRYB();
    G2_RDA(aC_); G2_RDB(bC_, 0);
    if (s1) { G2_SA(aN_, t + 1); G2_SB(bN_, 0, t + 1); }
    G2_MMA(0);
    // p1 (N1): needs B1(t); A reused in regs; stages B1(t+1)
    if (s1) { VMW(4); } else { VMW(0); }
    ENTRYB();
    G2_RDB(bC_, 1);
    if (s1) G2_SB(bN_, 1, t + 1);
    G2_MMA(1);
    u16* tp;
    tp = aC_; aC_ = aN_; aN_ = tp;
    tp = bC_; bC_ = bN_; bN_ = tp;
  }

  // epilogue
  float b2c[2][2][NEXP];
  if (!accum) {
#pragma unroll
    for (int nh = 0; nh < 2; ++nh)
#pragma unroll
      for (int n = 0; n < 2; ++n)
#pragma unroll
        for (int e = 0; e < NEXP; ++e)
          b2c[nh][n][e] = bias[(size_t)e * DDIM + bn + nh * 128 + wn * 32 + n * 16 + fr];
  }
#pragma unroll
  for (int NH = 0; NH < 2; ++NH) {
    const int cb0 = bn + NH * 128 + wn * 32;
#pragma unroll
    for (int i = 0; i < 4; ++i) {
#pragma unroll
      for (int j = 0; j < 4; ++j) {
        const int r = bm + wm * 64 + i * 16 + fq * 4 + j;
        if (!accum) {
          float g8[NEXP];
#pragma unroll
          for (int e = 0; e < NEXP; ++e) g8[e] = gate[(size_t)r * NEXP + e];
#pragma unroll
          for (int n = 0; n < 2; ++n) {
            float v = acc[NH][i][n][j];
#pragma unroll
            for (int e = 0; e < NEXP; ++e) v += g8[e] * b2c[NH][n][e];
            Cout[(size_t)r * DDIM + cb0 + n * 16 + fr] = v;
          }
        } else {
#pragma unroll
          for (int n = 0; n < 2; ++n) {
            const size_t idx = (size_t)r * DDIM + cb0 + n * 16 + fr;
            Cout[idx] += acc[NH][i][n][j];
          }
        }
      }
    }
  }
#undef G2_BOFF
#undef G2_SA
#undef G2_SB
#undef G2_RDA
#undef G2_RDB
#undef G2_MMA
}

extern "C" void kernel_launch(void* const* d_in, const int* in_sizes, int n_in,
                              void* d_out, int out_size, void* d_ws, size_t ws_size,
                              hipStream_t stream) {
  (void)in_sizes; (void)n_in; (void)out_size;
  const float* x  = (const float*)d_in[0];   // [N, D]
  const float* W1 = (const float*)d_in[1];   // [E, D, H]
  const float* b1 = (const float*)d_in[2];   // [E, H]
  const float* W2 = (const float*)d_in[3];   // [E, H, D]
  const float* b2 = (const float*)d_in[4];   // [E, D]
  const float* Wg = (const float*)d_in[5];   // [D, E]
  const float* bg = (const float*)d_in[6];   // [E]
  float* out = (float*)d_out;                // [N, D]

  size_t o_xb   = 0;
  size_t o_w1t  = o_xb  + (size_t)NTOK * DDIM * 2;          // xb   bf16 [N,D]
  size_t o_w2t  = o_w1t + (size_t)NEXP * HDIM * DDIM * 2;   // W1t  bf16 [E*H, D]
  size_t o_gate = o_w2t + (size_t)NEXP * DDIM * HDIM * 2;   // W2t  bf16 [E][D][H]
  size_t o_h    = o_gate + (size_t)NTOK * NEXP * 4;         // gate f32  [N, E]
  size_t need   = o_h   + (size_t)NTOK * GEXP * HDIM * 2;   // h'   bf16 [N, G*H]
  if (ws_size < need) return;

  u16*   xb   = (u16*)((char*)d_ws + o_xb);
  u16*   W1t  = (u16*)((char*)d_ws + o_w1t);
  u16*   W2t  = (u16*)((char*)d_ws + o_w2t);
  float* gate = (float*)((char*)d_ws + o_gate);
  u16*   hbuf = (u16*)((char*)d_ws + o_h);

  k_prep<<<NTOK / 4, 256, 0, stream>>>(x, Wg, bg, xb, gate);
  dim3 g1(DDIM / 64, HDIM / 64, NEXP);
  k_transpose<<<g1, 256, 0, stream>>>(W1, W1t, DDIM, HDIM, (size_t)HDIM * DDIM, DDIM);
  dim3 g2(HDIM / 64, DDIM / 64, NEXP);
  k_transpose<<<g2, 256, 0, stream>>>(W2, W2t, HDIM, DDIM, (size_t)DDIM * HDIM, HDIM);

  const int Ng = GEXP * HDIM;                  // 4096
  for (int g = 0; g < NEXP / GEXP; ++g) {
    k_g1<<<512, 512, 0, stream>>>(
        xb, W1t + (size_t)g * Ng * DDIM,
        b1 + (size_t)g * Ng, gate, g * GEXP, hbuf);
    k_g2<<<256, 512, 0, stream>>>(
        hbuf, W2t + (size_t)g * GEXP * DDIM * HDIM,
        b2, gate, out, g > 0);
  }
}

// Round 11
// 589.513 us; speedup vs baseline: 2.3000x; 1.0700x over previous
//
#include <hip/hip_runtime.h>

#define NTOK 8192
#define DDIM 1024
#define HDIM 2048
#define NEXP 8
#define G1_NKT 16               // GEMM1 K=1024 / 64

typedef unsigned short u16;
typedef short bf16x8 __attribute__((ext_vector_type(8)));
typedef float f32x4 __attribute__((ext_vector_type(4)));
typedef float float4_t __attribute__((ext_vector_type(4)));

__device__ __forceinline__ u16 f2bf(float f) {
  unsigned u = __float_as_uint(f);
  u += 0x7FFFu + ((u >> 16) & 1u);   // round-to-nearest-even
  return (u16)(u >> 16);
}

#define GLOAD_LDS16(gp, lp)                                                     \
  __builtin_amdgcn_global_load_lds(                                             \
      (const __attribute__((address_space(1))) unsigned int*)(gp),              \
      (__attribute__((address_space(3))) unsigned int*)(lp), 16, 0, 0)

#define VMW(n) asm volatile("s_waitcnt vmcnt(" #n ")" ::: "memory")
#define ENTRYB()                                                                \
  { __builtin_amdgcn_s_barrier(); __builtin_amdgcn_sched_barrier(0); }

// ------------------------------------------------ fused x->bf16 convert + gate
__global__ void k_prep(const float* __restrict__ x, const float* __restrict__ Wg,
                       const float* __restrict__ bg,
                       u16* __restrict__ xb, float* __restrict__ gate) {
  const int tok = (blockIdx.x * 256 + threadIdx.x) >> 6;
  const int lane = threadIdx.x & 63;
  const float* xr = x + (size_t)tok * DDIM;
  u16* xo = xb + (size_t)tok * DDIM;
  float s[NEXP];
#pragma unroll
  for (int e = 0; e < NEXP; ++e) s[e] = 0.f;
#pragma unroll
  for (int it = 0; it < 2; ++it) {
    const int d0 = lane * 8 + it * 512;
    float4_t v0 = *(const float4_t*)(xr + d0);
    float4_t v1 = *(const float4_t*)(xr + d0 + 4);
    union { bf16x8 v; u16 h[8]; } u;
    u.h[0] = f2bf(v0.x); u.h[1] = f2bf(v0.y); u.h[2] = f2bf(v0.z); u.h[3] = f2bf(v0.w);
    u.h[4] = f2bf(v1.x); u.h[5] = f2bf(v1.y); u.h[6] = f2bf(v1.z); u.h[7] = f2bf(v1.w);
    *(bf16x8*)(xo + d0) = u.v;
    float xv[8] = {v0.x, v0.y, v0.z, v0.w, v1.x, v1.y, v1.z, v1.w};
#pragma unroll
    for (int j = 0; j < 8; ++j) {
      const float4_t w0 = *(const float4_t*)(Wg + (size_t)(d0 + j) * NEXP);
      const float4_t w1 = *(const float4_t*)(Wg + (size_t)(d0 + j) * NEXP + 4);
      s[0] += xv[j] * w0.x; s[1] += xv[j] * w0.y;
      s[2] += xv[j] * w0.z; s[3] += xv[j] * w0.w;
      s[4] += xv[j] * w1.x; s[5] += xv[j] * w1.y;
      s[6] += xv[j] * w1.z; s[7] += xv[j] * w1.w;
    }
  }
#pragma unroll
  for (int off = 32; off; off >>= 1)
#pragma unroll
    for (int e = 0; e < NEXP; ++e) s[e] += __shfl_down(s[e], off);
  if (lane == 0) {
#pragma unroll
    for (int e = 0; e < NEXP; ++e) gate[(size_t)tok * NEXP + e] = s[e] + bg[e];
  }
}

// ------------- vectorized transpose+convert: out[z*oexp + c*orstride + r] = in[z][r][c]
__global__ void k_transpose(const float* __restrict__ in, u16* __restrict__ out,
                            int R, int C, size_t oexp, int orstride) {
  __shared__ float t[64][65];
  const int rb = blockIdx.x * 64, cb = blockIdx.y * 64;
  const float* pin = in + (size_t)blockIdx.z * R * C;
  u16* pout = out + (size_t)blockIdx.z * oexp;
  const int tid = threadIdx.x;
  {
    const int r = tid >> 4;
    const int c4 = (tid & 15) * 4;
#pragma unroll
    for (int i = 0; i < 4; ++i) {
      float4_t v = *(const float4_t*)(pin + (size_t)(rb + r + 16 * i) * C + cb + c4);
      t[r + 16 * i][c4 + 0] = v.x;
      t[r + 16 * i][c4 + 1] = v.y;
      t[r + 16 * i][c4 + 2] = v.z;
      t[r + 16 * i][c4 + 3] = v.w;
    }
  }
  __syncthreads();
  {
    const int oc = tid >> 3;
    const int r8 = (tid & 7) * 8;
#pragma unroll
    for (int jp = 0; jp < 2; ++jp) {
      const int ocol = oc + 32 * jp;
      union { bf16x8 v; u16 h[8]; } u;
#pragma unroll
      for (int k = 0; k < 8; ++k) u.h[k] = f2bf(t[r8 + k][ocol]);
      *(bf16x8*)(pout + (size_t)(cb + ocol) * orstride + rb + r8) = u.v;
    }
  }
}

// ============ GEMM1: 256x256 tile, 4-phase snake, kk-ordered reads + kk-outer MFMA
// h'[m][KW] = bf16(gate * relu(x . W1t^T + b1))
__global__ __launch_bounds__(512, 2) void k_g1(
    const u16* __restrict__ A, const u16* __restrict__ Bt,
    const float* __restrict__ bias, const float* __restrict__ gate,
    int ebase, u16* __restrict__ Cout, int KW, int ca, int cgcols) {
  __shared__ __align__(16) u16 lds[65536];   // 128 KiB: 2 buf x (A 256 | B 256) x 64
  const int tid = threadIdx.x, lane = tid & 63, wid = tid >> 6;
  const int wm = wid >> 2, wn = wid & 3;
  // XCD supertile: chunks of ca x 8, tn-inner
  const int wg = blockIdx.x;
  const int xcd = wg & 7, lo = wg >> 3;
  const int cr = xcd / cgcols, cc = xcd % cgcols;
  const int tm = cr * ca + (lo >> 3);
  const int tn = cc * 8 + (lo & 7);
  const int bm = tm * 256, bn = tn * 256;

  const int srow = tid >> 3;
  const int scol = ((tid & 7) ^ (srow & 7)) << 3;
  const u16* gA = A + (size_t)(bm + srow) * 1024 + scol;
  const u16* gB = Bt + (size_t)(bn + srow) * 1024 + scol;
  const int dofs = wid * 512;

  u16* aB0 = lds;          u16* bB0 = lds + 16384;
  u16* aB1 = lds + 32768;  u16* bB1 = lds + 49152;

  const int fr = lane & 15, fq = lane >> 4, xr = fr & 7;
  const int so0 = ((0 + fq) ^ xr) << 3;
  const int so1 = ((4 + fq) ^ xr) << 3;

  f32x4 acc[4][4][2] = {};
  bf16x8 av[4][2], bv[2][2];

#define G1_SA(dst, hh, ts)                                                      \
  { GLOAD_LDS16(gA + (size_t)((hh)*128     ) * 1024 + (size_t)(ts) * 64,        \
                (dst) + ((hh)*128     ) * 64 + dofs);                           \
    GLOAD_LDS16(gA + (size_t)((hh)*128 + 64) * 1024 + (size_t)(ts) * 64,        \
                (dst) + ((hh)*128 + 64) * 64 + dofs); }
#define G1_SB(dst, hh, ts)                                                      \
  { GLOAD_LDS16(gB + (size_t)((hh)*128     ) * 1024 + (size_t)(ts) * 64,        \
                (dst) + ((hh)*128     ) * 64 + dofs);                           \
    GLOAD_LDS16(gB + (size_t)((hh)*128 + 64) * 1024 + (size_t)(ts) * 64,        \
                (dst) + ((hh)*128 + 64) * 64 + dofs); }
// kk-ordered reads: all so0 (kk0) first, then all so1 (kk1)
#define RD_A_K(src, MH, KK)                                                     \
  { _Pragma("unroll") for (int i_ = 0; i_ < 4; ++i_) {                          \
      const int rb_ = ((MH)*128 + wm * 64 + i_ * 16 + fr) << 6;                 \
      av[i_][KK] = *(const bf16x8*)((src) + rb_ + ((KK) ? so1 : so0)); } }
#define RD_B_K(src, NH, KK)                                                     \
  { _Pragma("unroll") for (int n_ = 0; n_ < 2; ++n_) {                          \
      const int rb_ = ((NH)*128 + wn * 32 + n_ * 16 + fr) << 6;                 \
      bv[n_][KK] = *(const bf16x8*)((src) + rb_ + ((KK) ? so1 : so0)); } }
// kk-outer MFMA: kk0 cluster (needs only so0 reads), then kk1 cluster
#define MMA16(Q)                                                                \
  { __builtin_amdgcn_s_setprio(1);                                              \
    _Pragma("unroll") for (int k_ = 0; k_ < 2; ++k_)                            \
    _Pragma("unroll") for (int i_ = 0; i_ < 4; ++i_)                            \
    _Pragma("unroll") for (int n_ = 0; n_ < 2; ++n_)                            \
      acc[Q][i_][n_] = __builtin_amdgcn_mfma_f32_16x16x32_bf16(                 \
          av[i_][k_], bv[n_][k_], acc[Q][i_][n_], 0, 0, 0);                     \
    __builtin_amdgcn_s_setprio(0); }

  // prologue: tile0, issue order A0,B0,A1,B1 (matches steady-state order)
  G1_SA(aB0, 0, 0); G1_SB(bB0, 0, 0); G1_SA(aB0, 1, 0); G1_SB(bB0, 1, 0);

  u16 *aC_ = aB0, *bC_ = bB0, *aN_ = aB1, *bN_ = bB1;

#pragma unroll 1
  for (int t = 0; t < G1_NKT; ++t) {
    const bool s1 = (t + 1 < G1_NKT);
    // p0 = (M0,N0): needs A0(t),B0(t); stages A0(t+1)
    VMW(4); ENTRYB();
    RD_A_K(aC_, 0, 0); RD_B_K(bC_, 0, 0);
    RD_A_K(aC_, 0, 1); RD_B_K(bC_, 0, 1);
    if (s1) G1_SA(aN_, 0, t + 1);
    MMA16(0);
    // p1 = (M1,N0): needs A1(t); B0 reused in regs; stages B0(t+1)
    if (s1) { VMW(4); } else { VMW(2); }
    ENTRYB();
    RD_A_K(aC_, 1, 0); RD_A_K(aC_, 1, 1);
    if (s1) G1_SB(bN_, 0, t + 1);
    MMA16(2);
    // p2 = (M1,N1): needs B1(t); A1 reused; stages A1(t+1)
    if (s1) { VMW(4); } else { VMW(0); }
    ENTRYB();
    RD_B_K(bC_, 1, 0); RD_B_K(bC_, 1, 1);
    if (s1) G1_SA(aN_, 1, t + 1);
    MMA16(3);
    // p3 = (M0,N1): re-reads A0(t) (stable); B1 reused; stages B1(t+1); NO barrier
    RD_A_K(aC_, 0, 0); RD_A_K(aC_, 0, 1);
    if (s1) G1_SB(bN_, 1, t + 1);
    MMA16(1);
    u16* tp;
    tp = aC_; aC_ = aN_; aN_ = tp;
    tp = bC_; bC_ = bN_; bN_ = tp;
  }

  // epilogue; C/D layout: col=lane&15, row=(lane>>4)*4+j
#pragma unroll
  for (int q = 0; q < 4; ++q) {
    const int MH = q >> 1, NH = q & 1;
    const int cb0 = bn + NH * 128 + wn * 32;
    const int e = ebase + (cb0 >> 11);
    float bcol[2];
#pragma unroll
    for (int n = 0; n < 2; ++n) bcol[n] = bias[cb0 + n * 16 + fr];
#pragma unroll
    for (int i = 0; i < 4; ++i) {
#pragma unroll
      for (int j = 0; j < 4; ++j) {
        const int r = bm + MH * 128 + wm * 64 + i * 16 + fq * 4 + j;
        const float g = gate[(size_t)r * NEXP + e];
#pragma unroll
        for (int n = 0; n < 2; ++n) {
          float v = fmaxf(acc[q][i][n][j] + bcol[n], 0.f) * g;
          Cout[(size_t)r * KW + cb0 + n * 16 + fr] = f2bf(v);
        }
      }
    }
  }
#undef G1_SA
#undef G1_SB
#undef RD_A_K
#undef RD_B_K
#undef MMA16
}

// ============ GEMM2: 128x256 tile, 2 fat phases, kk-ordered reads + kk-outer MFMA
// out[m][1024] (+)= h'[m][KW] . W2t^T  (+ sum_e gate*b2 when !accum)
__global__ __launch_bounds__(512, 2) void k_g2(
    const u16* __restrict__ A, const u16* __restrict__ Bt,
    const float* __restrict__ bias, const float* __restrict__ gate,
    float* __restrict__ Cout, int accum, int KW, int nk) {
  __shared__ __align__(16) u16 lds[49152];   // 96 KiB: 2 buf x (A 128 | B 256) x 64
  const int tid = threadIdx.x, lane = tid & 63, wid = tid >> 6;
  const int wm = wid >> 2, wn = wid & 3;
  // XCD supertile: 64tm x 4tn grid; 8 chunks of 8x4, tn-inner
  const int wg = blockIdx.x;
  const int xcd = wg & 7, lo = wg >> 3;
  const int tm = xcd * 8 + (lo >> 2);
  const int tn = lo & 3;
  const int bm = tm * 128, bn = tn * 256;

  const int srow = tid >> 3;
  const int scol = ((tid & 7) ^ (srow & 7)) << 3;
  const u16* gA = A + (size_t)(bm + srow) * KW + scol;
  const u16* gB = Bt + (size_t)(bn + srow) * HDIM + scol;
  const int dofs = wid * 512;

  u16* aB0 = lds;          u16* bB0 = lds + 8192;
  u16* aB1 = lds + 24576;  u16* bB1 = lds + 32768;

  const int fr = lane & 15, fq = lane >> 4, xr = fr & 7;
  const int so0 = ((0 + fq) ^ xr) << 3;
  const int so1 = ((4 + fq) ^ xr) << 3;

  f32x4 acc[2][4][2] = {};
  bf16x8 av[4][2], bv[2][2];

#define G2_BOFF(ts) ((size_t)((ts) >> 5) * ((size_t)DDIM * HDIM) +              \
                     (size_t)((ts) & 31) * 64)
#define G2_SA(dst, ts)                                                          \
  { GLOAD_LDS16(gA + (size_t)(ts) * 64, (dst) + dofs);                          \
    GLOAD_LDS16(gA + (size_t)64 * KW + (size_t)(ts) * 64,                       \
                (dst) + 4096 + dofs); }
#define G2_SB(dst, hh, ts)                                                      \
  { GLOAD_LDS16(gB + (size_t)((hh)*128     ) * HDIM + G2_BOFF(ts),              \
                (dst) + ((hh)*128     ) * 64 + dofs);                           \
    GLOAD_LDS16(gB + (size_t)((hh)*128 + 64) * HDIM + G2_BOFF(ts),              \
                (dst) + ((hh)*128 + 64) * 64 + dofs); }
#define G2_RDA_K(src, KK)                                                       \
  { _Pragma("unroll") for (int i_ = 0; i_ < 4; ++i_) {                          \
      const int rb_ = (wm * 64 + i_ * 16 + fr) << 6;                            \
      av[i_][KK] = *(const bf16x8*)((src) + rb_ + ((KK) ? so1 : so0)); } }
#define G2_RDB_K(src, NH, KK)                                                   \
  { _Pragma("unroll") for (int n_ = 0; n_ < 2; ++n_) {                          \
      const int rb_ = ((NH)*128 + wn * 32 + n_ * 16 + fr) << 6;                 \
      bv[n_][KK] = *(const bf16x8*)((src) + rb_ + ((KK) ? so1 : so0)); } }
#define G2_MMA(Q)                                                               \
  { __builtin_amdgcn_s_setprio(1);                                              \
    _Pragma("unroll") for (int k_ = 0; k_ < 2; ++k_)                            \
    _Pragma("unroll") for (int i_ = 0; i_ < 4; ++i_)                            \
    _Pragma("unroll") for (int n_ = 0; n_ < 2; ++n_)                            \
      acc[Q][i_][n_] = __builtin_amdgcn_mfma_f32_16x16x32_bf16(                 \
          av[i_][k_], bv[n_][k_], acc[Q][i_][n_], 0, 0, 0);                     \
    __builtin_amdgcn_s_setprio(0); }

  // prologue: tile0, issue order A,B0,B1 (matches steady state)
  G2_SA(aB0, 0); G2_SB(bB0, 0, 0); G2_SB(bB0, 1, 0);

  u16 *aC_ = aB0, *bC_ = bB0, *aN_ = aB1, *bN_ = bB1;

#pragma unroll 1
  for (int t = 0; t < nk; ++t) {
    const bool s1 = (t + 1 < nk);
    // p0 (N0): needs A(t),B0(t); stages A(t+1)+B0(t+1)
    VMW(2); ENTRYB();
    G2_RDA_K(aC_, 0); G2_RDB_K(bC_, 0, 0);
    G2_RDA_K(aC_, 1); G2_RDB_K(bC_, 0, 1);
    if (s1) { G2_SA(aN_, t + 1); G2_SB(bN_, 0, t + 1); }
    G2_MMA(0);
    // p1 (N1): needs B1(t); A reused in regs; stages B1(t+1)
    if (s1) { VMW(4); } else { VMW(0); }
    ENTRYB();
    G2_RDB_K(bC_, 1, 0); G2_RDB_K(bC_, 1, 1);
    if (s1) G2_SB(bN_, 1, t + 1);
    G2_MMA(1);
    u16* tp;
    tp = aC_; aC_ = aN_; aN_ = tp;
    tp = bC_; bC_ = bN_; bN_ = tp;
  }

  // epilogue
  float b2c[2][2][NEXP];
  if (!accum) {
#pragma unroll
    for (int nh = 0; nh < 2; ++nh)
#pragma unroll
      for (int n = 0; n < 2; ++n)
#pragma unroll
        for (int e = 0; e < NEXP; ++e)
          b2c[nh][n][e] = bias[(size_t)e * DDIM + bn + nh * 128 + wn * 32 + n * 16 + fr];
  }
#pragma unroll
  for (int NH = 0; NH < 2; ++NH) {
    const int cb0 = bn + NH * 128 + wn * 32;
#pragma unroll
    for (int i = 0; i < 4; ++i) {
#pragma unroll
      for (int j = 0; j < 4; ++j) {
        const int r = bm + wm * 64 + i * 16 + fq * 4 + j;
        if (!accum) {
          float g8[NEXP];
#pragma unroll
          for (int e = 0; e < NEXP; ++e) g8[e] = gate[(size_t)r * NEXP + e];
#pragma unroll
          for (int n = 0; n < 2; ++n) {
            float v = acc[NH][i][n][j];
#pragma unroll
            for (int e = 0; e < NEXP; ++e) v += g8[e] * b2c[NH][n][e];
            Cout[(size_t)r * DDIM + cb0 + n * 16 + fr] = v;
          }
        } else {
#pragma unroll
          for (int n = 0; n < 2; ++n) {
            const size_t idx = (size_t)r * DDIM + cb0 + n * 16 + fr;
            Cout[idx] += acc[NH][i][n][j];
          }
        }
      }
    }
  }
#undef G2_BOFF
#undef G2_SA
#undef G2_SB
#undef G2_RDA_K
#undef G2_RDB_K
#undef G2_MMA
}

extern "C" void kernel_launch(void* const* d_in, const int* in_sizes, int n_in,
                              void* d_out, int out_size, void* d_ws, size_t ws_size,
                              hipStream_t stream) {
  (void)in_sizes; (void)n_in; (void)out_size;
  const float* x  = (const float*)d_in[0];   // [N, D]
  const float* W1 = (const float*)d_in[1];   // [E, D, H]
  const float* b1 = (const float*)d_in[2];   // [E, H]
  const float* W2 = (const float*)d_in[3];   // [E, H, D]
  const float* b2 = (const float*)d_in[4];   // [E, D]
  const float* Wg = (const float*)d_in[5];   // [D, E]
  const float* bg = (const float*)d_in[6];   // [E]
  float* out = (float*)d_out;                // [N, D]

  size_t o_xb   = 0;
  size_t o_w1t  = o_xb  + (size_t)NTOK * DDIM * 2;          // xb   bf16 [N,D]
  size_t o_w2t  = o_w1t + (size_t)NEXP * HDIM * DDIM * 2;   // W1t  bf16 [E*H, D]
  size_t o_gate = o_w2t + (size_t)NEXP * DDIM * HDIM * 2;   // W2t  bf16 [E][D][H]
  size_t o_h    = o_gate + (size_t)NTOK * NEXP * 4;         // gate f32  [N, E]

  int G = 4;                                                 // experts per group
  if (o_h + (size_t)NTOK * G * HDIM * 2 > ws_size) G = 2;
  if (o_h + (size_t)NTOK * G * HDIM * 2 > ws_size) return;

  u16*   xb   = (u16*)((char*)d_ws + o_xb);
  u16*   W1t  = (u16*)((char*)d_ws + o_w1t);
  u16*   W2t  = (u16*)((char*)d_ws + o_w2t);
  float* gate = (float*)((char*)d_ws + o_gate);
  u16*   hbuf = (u16*)((char*)d_ws + o_h);

  k_prep<<<NTOK / 4, 256, 0, stream>>>(x, Wg, bg, xb, gate);
  dim3 g1(DDIM / 64, HDIM / 64, NEXP);
  k_transpose<<<g1, 256, 0, stream>>>(W1, W1t, DDIM, HDIM, (size_t)HDIM * DDIM, DDIM);
  dim3 g2(HDIM / 64, DDIM / 64, NEXP);
  k_transpose<<<g2, 256, 0, stream>>>(W2, W2t, HDIM, DDIM, (size_t)DDIM * HDIM, HDIM);

  const int KW = G * HDIM;                     // 8192 or 4096
  const int ca1 = (G == 4) ? 16 : 8;           // XCD chunk rows for GEMM1
  const int cg1 = (G == 4) ? 4 : 2;            // chunk-grid cols for GEMM1
  for (int g = 0; g < NEXP / G; ++g) {
    // GEMM1: grid 32tm x (KW/256)tn
    k_g1<<<(NTOK / 256) * (KW / 256), 512, 0, stream>>>(
        xb, W1t + (size_t)g * KW * DDIM,
        b1 + (size_t)g * KW, gate, g * G, hbuf, KW, ca1, cg1);
    // GEMM2: grid 256, K = KW
    k_g2<<<256, 512, 0, stream>>>(
        hbuf, W2t + (size_t)g * G * DDIM * HDIM,
        b2, gate, out, g > 0, KW, KW / 64);
  }
}

// Round 12
// 582.971 us; speedup vs baseline: 2.3258x; 1.0112x over previous
//
#include <hip/hip_runtime.h>

#define NTOK 8192
#define DDIM 1024
#define HDIM 2048
#define NEXP 8
#define G1_NKT 16               // GEMM1 K=1024 / 64

typedef unsigned short u16;
typedef short bf16x8 __attribute__((ext_vector_type(8)));
typedef float f32x4 __attribute__((ext_vector_type(4)));
typedef float float4_t __attribute__((ext_vector_type(4)));

__device__ __forceinline__ u16 f2bf(float f) {
  unsigned u = __float_as_uint(f);
  u += 0x7FFFu + ((u >> 16) & 1u);   // round-to-nearest-even
  return (u16)(u >> 16);
}

#define GLOAD_LDS16(gp, lp)                                                     \
  __builtin_amdgcn_global_load_lds(                                             \
      (const __attribute__((address_space(1))) unsigned int*)(gp),              \
      (__attribute__((address_space(3))) unsigned int*)(lp), 16, 0, 0)

#define VMW(n) asm volatile("s_waitcnt vmcnt(" #n ")" ::: "memory")
#define ENTRYB()                                                                \
  { __builtin_amdgcn_s_barrier(); __builtin_amdgcn_sched_barrier(0); }

// ------------------------------------------------ fused x->bf16 convert + gate
__global__ void k_prep(const float* __restrict__ x, const float* __restrict__ Wg,
                       const float* __restrict__ bg,
                       u16* __restrict__ xb, float* __restrict__ gate) {
  const int tok = (blockIdx.x * 256 + threadIdx.x) >> 6;
  const int lane = threadIdx.x & 63;
  const float* xr = x + (size_t)tok * DDIM;
  u16* xo = xb + (size_t)tok * DDIM;
  float s[NEXP];
#pragma unroll
  for (int e = 0; e < NEXP; ++e) s[e] = 0.f;
#pragma unroll
  for (int it = 0; it < 2; ++it) {
    const int d0 = lane * 8 + it * 512;
    float4_t v0 = *(const float4_t*)(xr + d0);
    float4_t v1 = *(const float4_t*)(xr + d0 + 4);
    union { bf16x8 v; u16 h[8]; } u;
    u.h[0] = f2bf(v0.x); u.h[1] = f2bf(v0.y); u.h[2] = f2bf(v0.z); u.h[3] = f2bf(v0.w);
    u.h[4] = f2bf(v1.x); u.h[5] = f2bf(v1.y); u.h[6] = f2bf(v1.z); u.h[7] = f2bf(v1.w);
    *(bf16x8*)(xo + d0) = u.v;
    float xv[8] = {v0.x, v0.y, v0.z, v0.w, v1.x, v1.y, v1.z, v1.w};
#pragma unroll
    for (int j = 0; j < 8; ++j) {
      const float4_t w0 = *(const float4_t*)(Wg + (size_t)(d0 + j) * NEXP);
      const float4_t w1 = *(const float4_t*)(Wg + (size_t)(d0 + j) * NEXP + 4);
      s[0] += xv[j] * w0.x; s[1] += xv[j] * w0.y;
      s[2] += xv[j] * w0.z; s[3] += xv[j] * w0.w;
      s[4] += xv[j] * w1.x; s[5] += xv[j] * w1.y;
      s[6] += xv[j] * w1.z; s[7] += xv[j] * w1.w;
    }
  }
#pragma unroll
  for (int off = 32; off; off >>= 1)
#pragma unroll
    for (int e = 0; e < NEXP; ++e) s[e] += __shfl_down(s[e], off);
  if (lane == 0) {
#pragma unroll
    for (int e = 0; e < NEXP; ++e) gate[(size_t)tok * NEXP + e] = s[e] + bg[e];
  }
}

// ------------- vectorized transpose+convert: out[z*oexp + c*orstride + r] = in[z][r][c]
__global__ void k_transpose(const float* __restrict__ in, u16* __restrict__ out,
                            int R, int C, size_t oexp, int orstride) {
  __shared__ float t[64][65];
  const int rb = blockIdx.x * 64, cb = blockIdx.y * 64;
  const float* pin = in + (size_t)blockIdx.z * R * C;
  u16* pout = out + (size_t)blockIdx.z * oexp;
  const int tid = threadIdx.x;
  {
    const int r = tid >> 4;
    const int c4 = (tid & 15) * 4;
#pragma unroll
    for (int i = 0; i < 4; ++i) {
      float4_t v = *(const float4_t*)(pin + (size_t)(rb + r + 16 * i) * C + cb + c4);
      t[r + 16 * i][c4 + 0] = v.x;
      t[r + 16 * i][c4 + 1] = v.y;
      t[r + 16 * i][c4 + 2] = v.z;
      t[r + 16 * i][c4 + 3] = v.w;
    }
  }
  __syncthreads();
  {
    const int oc = tid >> 3;
    const int r8 = (tid & 7) * 8;
#pragma unroll
    for (int jp = 0; jp < 2; ++jp) {
      const int ocol = oc + 32 * jp;
      union { bf16x8 v; u16 h[8]; } u;
#pragma unroll
      for (int k = 0; k < 8; ++k) u.h[k] = f2bf(t[r8 + k][ocol]);
      *(bf16x8*)(pout + (size_t)(cb + ocol) * orstride + rb + r8) = u.v;
    }
  }
}

// ============ GEMM1: 256x256 tile, 4-phase snake, kk-ordered reads + kk-outer MFMA
// h'[m][KW] = bf16(gate * relu(x . W1t^T + b1))
__global__ __launch_bounds__(512, 2) void k_g1(
    const u16* __restrict__ A, const u16* __restrict__ Bt,
    const float* __restrict__ bias, const float* __restrict__ gate,
    int ebase, u16* __restrict__ Cout, int KW, int ca, int cgcols) {
  __shared__ __align__(16) u16 lds[65536];   // 128 KiB: 2 buf x (A 256 | B 256) x 64
  const int tid = threadIdx.x, lane = tid & 63, wid = tid >> 6;
  const int wm = wid >> 2, wn = wid & 3;
  // XCD supertile: chunks of ca x 8, tn-inner
  const int wg = blockIdx.x;
  const int xcd = wg & 7, lo = wg >> 3;
  const int cr = xcd / cgcols, cc = xcd % cgcols;
  const int tm = cr * ca + (lo >> 3);
  const int tn = cc * 8 + (lo & 7);
  const int bm = tm * 256, bn = tn * 256;

  const int srow = tid >> 3;
  const int scol = ((tid & 7) ^ (srow & 7)) << 3;
  const u16* gA = A + (size_t)(bm + srow) * 1024 + scol;
  const u16* gB = Bt + (size_t)(bn + srow) * 1024 + scol;
  const int dofs = wid * 512;

  u16* aB0 = lds;          u16* bB0 = lds + 16384;
  u16* aB1 = lds + 32768;  u16* bB1 = lds + 49152;

  const int fr = lane & 15, fq = lane >> 4, xr = fr & 7;
  const int so0 = ((0 + fq) ^ xr) << 3;
  const int so1 = ((4 + fq) ^ xr) << 3;

  f32x4 acc[4][4][2] = {};
  bf16x8 av[4][2], bv[2][2];

#define G1_SA(dst, hh, ts)                                                      \
  { GLOAD_LDS16(gA + (size_t)((hh)*128     ) * 1024 + (size_t)(ts) * 64,        \
                (dst) + ((hh)*128     ) * 64 + dofs);                           \
    GLOAD_LDS16(gA + (size_t)((hh)*128 + 64) * 1024 + (size_t)(ts) * 64,        \
                (dst) + ((hh)*128 + 64) * 64 + dofs); }
#define G1_SB(dst, hh, ts)                                                      \
  { GLOAD_LDS16(gB + (size_t)((hh)*128     ) * 1024 + (size_t)(ts) * 64,        \
                (dst) + ((hh)*128     ) * 64 + dofs);                           \
    GLOAD_LDS16(gB + (size_t)((hh)*128 + 64) * 1024 + (size_t)(ts) * 64,        \
                (dst) + ((hh)*128 + 64) * 64 + dofs); }
// kk-ordered reads: all so0 (kk0) first, then all so1 (kk1)
#define RD_A_K(src, MH, KK)                                                     \
  { _Pragma("unroll") for (int i_ = 0; i_ < 4; ++i_) {                          \
      const int rb_ = ((MH)*128 + wm * 64 + i_ * 16 + fr) << 6;                 \
      av[i_][KK] = *(const bf16x8*)((src) + rb_ + ((KK) ? so1 : so0)); } }
#define RD_B_K(src, NH, KK)                                                     \
  { _Pragma("unroll") for (int n_ = 0; n_ < 2; ++n_) {                          \
      const int rb_ = ((NH)*128 + wn * 32 + n_ * 16 + fr) << 6;                 \
      bv[n_][KK] = *(const bf16x8*)((src) + rb_ + ((KK) ? so1 : so0)); } }
// kk-outer MFMA: kk0 cluster (needs only so0 reads), then kk1 cluster
#define MMA16(Q)                                                                \
  { __builtin_amdgcn_s_setprio(1);                                              \
    _Pragma("unroll") for (int k_ = 0; k_ < 2; ++k_)                            \
    _Pragma("unroll") for (int i_ = 0; i_ < 4; ++i_)                            \
    _Pragma("unroll") for (int n_ = 0; n_ < 2; ++n_)                            \
      acc[Q][i_][n_] = __builtin_amdgcn_mfma_f32_16x16x32_bf16(                 \
          av[i_][k_], bv[n_][k_], acc[Q][i_][n_], 0, 0, 0);                     \
    __builtin_amdgcn_s_setprio(0); }

  // prologue: tile0, issue order A0,B0,A1,B1 (matches steady-state order)
  G1_SA(aB0, 0, 0); G1_SB(bB0, 0, 0); G1_SA(aB0, 1, 0); G1_SB(bB0, 1, 0);

  u16 *aC_ = aB0, *bC_ = bB0, *aN_ = aB1, *bN_ = bB1;

#pragma unroll 1
  for (int t = 0; t < G1_NKT; ++t) {
    const bool s1 = (t + 1 < G1_NKT);
    // p0 = (M0,N0): needs A0(t),B0(t); stages A0(t+1)
    VMW(4); ENTRYB();
    RD_A_K(aC_, 0, 0); RD_B_K(bC_, 0, 0);
    RD_A_K(aC_, 0, 1); RD_B_K(bC_, 0, 1);
    if (s1) G1_SA(aN_, 0, t + 1);
    MMA16(0);
    // p1 = (M1,N0): needs A1(t); B0 reused in regs; stages B0(t+1)
    if (s1) { VMW(4); } else { VMW(2); }
    ENTRYB();
    RD_A_K(aC_, 1, 0); RD_A_K(aC_, 1, 1);
    if (s1) G1_SB(bN_, 0, t + 1);
    MMA16(2);
    // p2 = (M1,N1): needs B1(t); A1 reused; stages A1(t+1)
    if (s1) { VMW(4); } else { VMW(0); }
    ENTRYB();
    RD_B_K(bC_, 1, 0); RD_B_K(bC_, 1, 1);
    if (s1) G1_SA(aN_, 1, t + 1);
    MMA16(3);
    // p3 = (M0,N1): re-reads A0(t) (stable); B1 reused; stages B1(t+1); NO barrier
    RD_A_K(aC_, 0, 0); RD_A_K(aC_, 0, 1);
    if (s1) G1_SB(bN_, 1, t + 1);
    MMA16(1);
    u16* tp;
    tp = aC_; aC_ = aN_; aN_ = tp;
    tp = bC_; bC_ = bN_; bN_ = tp;
  }

  // epilogue; C/D layout: col=lane&15, row=(lane>>4)*4+j
#pragma unroll
  for (int q = 0; q < 4; ++q) {
    const int MH = q >> 1, NH = q & 1;
    const int cb0 = bn + NH * 128 + wn * 32;
    const int e = ebase + (cb0 >> 11);
    float bcol[2];
#pragma unroll
    for (int n = 0; n < 2; ++n) bcol[n] = bias[cb0 + n * 16 + fr];
#pragma unroll
    for (int i = 0; i < 4; ++i) {
#pragma unroll
      for (int j = 0; j < 4; ++j) {
        const int r = bm + MH * 128 + wm * 64 + i * 16 + fq * 4 + j;
        const float g = gate[(size_t)r * NEXP + e];
#pragma unroll
        for (int n = 0; n < 2; ++n) {
          float v = fmaxf(acc[q][i][n][j] + bcol[n], 0.f) * g;
          Cout[(size_t)r * KW + cb0 + n * 16 + fr] = f2bf(v);
        }
      }
    }
  }
#undef G1_SA
#undef G1_SB
#undef RD_A_K
#undef RD_B_K
#undef MMA16
}

// ============ GEMM2: 128x256 tile, lag-one pipeline: each phase's MFMA uses
// operands read the PREVIOUS phase (A reg-double-buffered), so ds_reads issue
// with no downstream dependency and overlap the MFMA cluster.
// out[m][1024] (+)= h'[m][KW] . W2t^T  (+ sum_e gate*b2 when !accum)
__global__ __launch_bounds__(512, 2) void k_g2(
    const u16* __restrict__ A, const u16* __restrict__ Bt,
    const float* __restrict__ bias, const float* __restrict__ gate,
    float* __restrict__ Cout, int accum, int KW, int nk) {
  __shared__ __align__(16) u16 lds[49152];   // 96 KiB: 2 buf x (A 128 | B 256) x 64
  const int tid = threadIdx.x, lane = tid & 63, wid = tid >> 6;
  const int wm = wid >> 2, wn = wid & 3;
  // XCD supertile: 64tm x 4tn grid; 8 chunks of 8x4, tn-inner
  const int wg = blockIdx.x;
  const int xcd = wg & 7, lo = wg >> 3;
  const int tm = xcd * 8 + (lo >> 2);
  const int tn = lo & 3;
  const int bm = tm * 128, bn = tn * 256;

  const int srow = tid >> 3;
  const int scol = ((tid & 7) ^ (srow & 7)) << 3;
  const u16* gA = A + (size_t)(bm + srow) * KW + scol;
  const u16* gB = Bt + (size_t)(bn + srow) * HDIM + scol;
  const int dofs = wid * 512;

  u16* aB0 = lds;          u16* bB0 = lds + 8192;
  u16* aB1 = lds + 24576;  u16* bB1 = lds + 32768;

  const int fr = lane & 15, fq = lane >> 4, xr = fr & 7;
  const int so0 = ((0 + fq) ^ xr) << 3;
  const int so1 = ((4 + fq) ^ xr) << 3;

  f32x4 acc[2][4][2] = {};
  bf16x8 avA[8], avB[8], bv0[2][2], bv1[2][2];

#define G2_BOFF(ts) ((size_t)((ts) >> 5) * ((size_t)DDIM * HDIM) +              \
                     (size_t)((ts) & 31) * 64)
#define G2_SA(dst, ts)                                                          \
  { GLOAD_LDS16(gA + (size_t)(ts) * 64, (dst) + dofs);                          \
    GLOAD_LDS16(gA + (size_t)64 * KW + (size_t)(ts) * 64,                       \
                (dst) + 4096 + dofs); }
#define G2_SB(dst, hh, ts)                                                      \
  { GLOAD_LDS16(gB + (size_t)((hh)*128     ) * HDIM + G2_BOFF(ts),              \
                (dst) + ((hh)*128     ) * 64 + dofs);                           \
    GLOAD_LDS16(gB + (size_t)((hh)*128 + 64) * HDIM + G2_BOFF(ts),              \
                (dst) + ((hh)*128 + 64) * 64 + dofs); }
#define G2_RDA_TO(DST, src)                                                     \
  { _Pragma("unroll") for (int i_ = 0; i_ < 4; ++i_) {                          \
      const int rb_ = (wm * 64 + i_ * 16 + fr) << 6;                            \
      (DST)[i_ * 2 + 0] = *(const bf16x8*)((src) + rb_ + so0);                  \
      (DST)[i_ * 2 + 1] = *(const bf16x8*)((src) + rb_ + so1); } }
#define G2_RDB_TO(DST, src, NH)                                                 \
  { _Pragma("unroll") for (int n_ = 0; n_ < 2; ++n_) {                          \
      const int rb_ = ((NH)*128 + wn * 32 + n_ * 16 + fr) << 6;                 \
      (DST)[n_][0] = *(const bf16x8*)((src) + rb_ + so0);                       \
      (DST)[n_][1] = *(const bf16x8*)((src) + rb_ + so1); } }
#define G2_MMA(Q, AV, BV)                                                       \
  { __builtin_amdgcn_s_setprio(1);                                              \
    _Pragma("unroll") for (int k_ = 0; k_ < 2; ++k_)                            \
    _Pragma("unroll") for (int i_ = 0; i_ < 4; ++i_)                            \
    _Pragma("unroll") for (int n_ = 0; n_ < 2; ++n_)                            \
      acc[Q][i_][n_] = __builtin_amdgcn_mfma_f32_16x16x32_bf16(                 \
          (AV)[i_ * 2 + k_], (BV)[n_][k_], acc[Q][i_][n_], 0, 0, 0);            \
    __builtin_amdgcn_s_setprio(0); }

// lag-one iteration: p0 reads A(t),B0(t) & computes N1(t-1); p1 reads B1(t)
// & computes N0(t). Stages target the opposite buffer only (race-safe: B1(t-1)
// region overwritten at p1(t), after the p1 barrier which implies all waves
// issued MFMA N1(t-1), hence their B1(t-1) ds_reads completed).
#define G2_ITER(T, AV, AVP, aCur, bCur, aNx, bNx)                               \
  {                                                                             \
    VMW(2); ENTRYB();                                                           \
    G2_RDA_TO(AV, aCur);                                                        \
    G2_RDB_TO(bv0, bCur, 0);                                                    \
    if ((T) + 1 < nk) { G2_SA(aNx, (T) + 1); G2_SB(bNx, 0, (T) + 1); }          \
    if ((T) > 0) G2_MMA(1, AVP, bv1);                                           \
    if ((T) + 1 < nk) { VMW(4); } else { VMW(0); }                              \
    ENTRYB();                                                                   \
    G2_RDB_TO(bv1, bCur, 1);                                                    \
    if ((T) + 1 < nk) G2_SB(bNx, 1, (T) + 1);                                   \
    G2_MMA(0, AV, bv0);                                                         \
  }

  // prologue: stage tile 0 only (A, B0, B1) -> 6 loads in flight
  G2_SA(aB0, 0); G2_SB(bB0, 0, 0); G2_SB(bB0, 1, 0);

#pragma unroll 1
  for (int tt = 0; tt < nk; tt += 2) {
    G2_ITER(tt,     avA, avB, aB0, bB0, aB1, bB1);
    G2_ITER(tt + 1, avB, avA, aB1, bB1, aB0, bB0);
  }
  // tail: N1 of the last tile (nk even -> last AV was avB, bv1 holds B1(nk-1))
  G2_MMA(1, avB, bv1);

  // epilogue
  float b2c[2][2][NEXP];
  if (!accum) {
#pragma unroll
    for (int nh = 0; nh < 2; ++nh)
#pragma unroll
      for (int n = 0; n < 2; ++n)
#pragma unroll
        for (int e = 0; e < NEXP; ++e)
          b2c[nh][n][e] = bias[(size_t)e * DDIM + bn + nh * 128 + wn * 32 + n * 16 + fr];
  }
#pragma unroll
  for (int NH = 0; NH < 2; ++NH) {
    const int cb0 = bn + NH * 128 + wn * 32;
#pragma unroll
    for (int i = 0; i < 4; ++i) {
#pragma unroll
      for (int j = 0; j < 4; ++j) {
        const int r = bm + wm * 64 + i * 16 + fq * 4 + j;
        if (!accum) {
          float g8[NEXP];
#pragma unroll
          for (int e = 0; e < NEXP; ++e) g8[e] = gate[(size_t)r * NEXP + e];
#pragma unroll
          for (int n = 0; n < 2; ++n) {
            float v = acc[NH][i][n][j];
#pragma unroll
            for (int e = 0; e < NEXP; ++e) v += g8[e] * b2c[NH][n][e];
            Cout[(size_t)r * DDIM + cb0 + n * 16 + fr] = v;
          }
        } else {
#pragma unroll
          for (int n = 0; n < 2; ++n) {
            const size_t idx = (size_t)r * DDIM + cb0 + n * 16 + fr;
            Cout[idx] += acc[NH][i][n][j];
          }
        }
      }
    }
  }
#undef G2_BOFF
#undef G2_SA
#undef G2_SB
#undef G2_RDA_TO
#undef G2_RDB_TO
#undef G2_MMA
#undef G2_ITER
}

extern "C" void kernel_launch(void* const* d_in, const int* in_sizes, int n_in,
                              void* d_out, int out_size, void* d_ws, size_t ws_size,
                              hipStream_t stream) {
  (void)in_sizes; (void)n_in; (void)out_size;
  const float* x  = (const float*)d_in[0];   // [N, D]
  const float* W1 = (const float*)d_in[1];   // [E, D, H]
  const float* b1 = (const float*)d_in[2];   // [E, H]
  const float* W2 = (const float*)d_in[3];   // [E, H, D]
  const float* b2 = (const float*)d_in[4];   // [E, D]
  const float* Wg = (const float*)d_in[5];   // [D, E]
  const float* bg = (const float*)d_in[6];   // [E]
  float* out = (float*)d_out;                // [N, D]

  size_t o_xb   = 0;
  size_t o_w1t  = o_xb  + (size_t)NTOK * DDIM * 2;          // xb   bf16 [N,D]
  size_t o_w2t  = o_w1t + (size_t)NEXP * HDIM * DDIM * 2;   // W1t  bf16 [E*H, D]
  size_t o_gate = o_w2t + (size_t)NEXP * DDIM * HDIM * 2;   // W2t  bf16 [E][D][H]
  size_t o_h    = o_gate + (size_t)NTOK * NEXP * 4;         // gate f32  [N, E]

  int G = 4;                                                 // experts per group
  if (o_h + (size_t)NTOK * G * HDIM * 2 > ws_size) G = 2;
  if (o_h + (size_t)NTOK * G * HDIM * 2 > ws_size) return;

  u16*   xb   = (u16*)((char*)d_ws + o_xb);
  u16*   W1t  = (u16*)((char*)d_ws + o_w1t);
  u16*   W2t  = (u16*)((char*)d_ws + o_w2t);
  float* gate = (float*)((char*)d_ws + o_gate);
  u16*   hbuf = (u16*)((char*)d_ws + o_h);

  k_prep<<<NTOK / 4, 256, 0, stream>>>(x, Wg, bg, xb, gate);
  dim3 g1(DDIM / 64, HDIM / 64, NEXP);
  k_transpose<<<g1, 256, 0, stream>>>(W1, W1t, DDIM, HDIM, (size_t)HDIM * DDIM, DDIM);
  dim3 g2(HDIM / 64, DDIM / 64, NEXP);
  k_transpose<<<g2, 256, 0, stream>>>(W2, W2t, HDIM, DDIM, (size_t)DDIM * HDIM, HDIM);

  const int KW = G * HDIM;                     // 8192 or 4096
  const int ca1 = (G == 4) ? 16 : 8;           // XCD chunk rows for GEMM1
  const int cg1 = (G == 4) ? 4 : 2;            // chunk-grid cols for GEMM1
  for (int g = 0; g < NEXP / G; ++g) {
    // GEMM1: grid 32tm x (KW/256)tn
    k_g1<<<(NTOK / 256) * (KW / 256), 512, 0, stream>>>(
        xb, W1t + (size_t)g * KW * DDIM,
        b1 + (size_t)g * KW, gate, g * G, hbuf, KW, ca1, cg1);
    // GEMM2: grid 256, K = KW
    k_g2<<<256, 512, 0, stream>>>(
        hbuf, W2t + (size_t)g * G * DDIM * HDIM,
        b2, gate, out, g > 0, KW, KW / 64);
  }
}